// Round 1
// baseline (352.475 us; speedup 1.0000x reference)
//
#include <hip/hip_runtime.h>

// Problem constants: x [B=2, C=512, H=64, W=64], 32 groups, N = H*W = 4096.
#define BB 2
#define CC 512
#define NS 4096
#define NGROUP 32
#define TILE 128
#define BK 32

typedef __bf16 bf16_8 __attribute__((ext_vector_type(8)));
typedef __bf16 bf16_4 __attribute__((ext_vector_type(4)));
typedef float f32_4 __attribute__((ext_vector_type(4)));

__device__ inline void gld_lds16(const __bf16* g, __bf16* l) {
  __builtin_amdgcn_global_load_lds(
      (const __attribute__((address_space(1))) unsigned int*)g,
      (__attribute__((address_space(3))) unsigned int*)l, 16, 0, 0);
}

// ---------------- GroupNorm ----------------
// One block per (b, group): 16 channels x 4096 = 65536 contiguous floats.
__global__ __launch_bounds__(256) void gn_stats(const float* __restrict__ x,
                                                float* __restrict__ stats) {
  const float4* p = (const float4*)(x + (size_t)blockIdx.x * 65536);
  float s = 0.f, q = 0.f;
  for (int i = threadIdx.x; i < 16384; i += 256) {
    float4 v = p[i];
    s += v.x + v.y + v.z + v.w;
    q += v.x * v.x + v.y * v.y + v.z * v.z + v.w * v.w;
  }
#pragma unroll
  for (int off = 32; off > 0; off >>= 1) {
    s += __shfl_down(s, off, 64);
    q += __shfl_down(q, off, 64);
  }
  __shared__ float ls[4], lq[4];
  int wave = threadIdx.x >> 6, lane = threadIdx.x & 63;
  if (lane == 0) { ls[wave] = s; lq[wave] = q; }
  __syncthreads();
  if (threadIdx.x == 0) {
    float S = ls[0] + ls[1] + ls[2] + ls[3];
    float Q = lq[0] + lq[1] + lq[2] + lq[3];
    float mean = S * (1.f / 65536.f);
    float var = Q * (1.f / 65536.f) - mean * mean;
    stats[blockIdx.x * 2] = mean;
    stats[blockIdx.x * 2 + 1] = rsqrtf(var + 1e-6f);
  }
}

// Normalize + transpose: x[b][c][n] (fp32) -> hnT[b][n][c] (bf16), 32x32 tiles via LDS.
__global__ __launch_bounds__(256) void gn_apply_t(const float* __restrict__ x,
                                                  const float* __restrict__ stats,
                                                  const float* __restrict__ gamma,
                                                  const float* __restrict__ beta,
                                                  __bf16* __restrict__ hnT) {
  __shared__ float tile[32][33];
  int b = blockIdx.z;
  int c0 = blockIdx.y * 32;
  int n0 = blockIdx.x * 32;
  int tx = threadIdx.x;  // 0..31
  int ty = threadIdx.y;  // 0..7
  const float* xb = x + (size_t)b * CC * NS;
#pragma unroll
  for (int i = 0; i < 4; i++) {
    int c = c0 + ty + i * 8;
    float mean = stats[(b * NGROUP + (c >> 4)) * 2 + 0];
    float rstd = stats[(b * NGROUP + (c >> 4)) * 2 + 1];
    float v = xb[(size_t)c * NS + n0 + tx];
    tile[ty + i * 8][tx] = (v - mean) * rstd * gamma[c] + beta[c];
  }
  __syncthreads();
  __bf16* out = hnT + (size_t)b * NS * CC;
#pragma unroll
  for (int i = 0; i < 4; i++) {
    int n = n0 + ty + i * 8;
    out[(size_t)n * CC + c0 + tx] = (__bf16)tile[tx][ty + i * 8];
  }
}

// fp32 -> bf16 weight conversion for the four 512x512 weights.
__global__ __launch_bounds__(256) void cvt_w(const float* __restrict__ w0, const float* __restrict__ w1,
                                             const float* __restrict__ w2, const float* __restrict__ w3,
                                             __bf16* __restrict__ o0, __bf16* __restrict__ o1,
                                             __bf16* __restrict__ o2, __bf16* __restrict__ o3) {
  int tsel = blockIdx.x >> 8;                       // 256 blocks per tensor
  int i = (blockIdx.x & 255) * 256 + threadIdx.x;   // float4 index, 65536 per tensor
  const float* src = tsel == 0 ? w0 : tsel == 1 ? w1 : tsel == 2 ? w2 : w3;
  __bf16* dst = tsel == 0 ? o0 : tsel == 1 ? o1 : tsel == 2 ? o2 : o3;
  float4 v = ((const float4*)src)[i];
  bf16_4 r;
  r[0] = (__bf16)v.x; r[1] = (__bf16)v.y; r[2] = (__bf16)v.z; r[3] = (__bf16)v.w;
  ((bf16_4*)dst)[i] = r;
}

// ---------------- GEMM: C[m,n] = alpha * sum_k A[m,k]*B[n,k] (+bias, +resid) ----------
// A: [M,K] row-major bf16 (lda=K), B: [N,K] row-major bf16 (ldb=K), C: [M,N] (ldc=N).
// 128x128 block tile, 4 waves as 2x2, each wave 64x64 via 4x4 mfma_f32_16x16x32_bf16.
template <bool OUT_BF16, int BIAS_MODE /*0 none,1 col,2 row*/, bool RESID>
__global__ __launch_bounds__(256) void gemm_bt(const __bf16* __restrict__ A,
                                               const __bf16* __restrict__ B,
                                               void* __restrict__ Cout,
                                               const float* __restrict__ bias,
                                               const float* __restrict__ resid,
                                               int N, int K,
                                               long long strideA, long long strideB,
                                               long long strideC, long long strideR,
                                               float alpha) {
  __shared__ __bf16 lA[TILE * BK];
  __shared__ __bf16 lB[TILE * BK];
  const int t = threadIdx.x;
  const int b = blockIdx.z;
  const int m0 = blockIdx.y * TILE;
  const int n0 = blockIdx.x * TILE;
  A += (size_t)b * strideA;
  B += (size_t)b * strideB;

  const int wave = t >> 6;
  const int lane = t & 63;
  const int lrow = lane & 15;
  const int quad = lane >> 4;
  const int wrow = (wave >> 1) * 64;
  const int wcol = (wave & 1) * 64;

  f32_4 acc[4][4];
#pragma unroll
  for (int i = 0; i < 4; i++)
#pragma unroll
    for (int j = 0; j < 4; j++) acc[i][j] = {0.f, 0.f, 0.f, 0.f};

  for (int k0 = 0; k0 < K; k0 += BK) {
    __syncthreads();
    // Stage A and B tiles: 128 rows x 32 cols bf16 = 8 KB each = 2 issues x 256 thr x 16B.
    // chunk c: row = c>>2, kchunk = c&3 (16B = 8 bf16 each). LDS layout row-major [128][32].
#pragma unroll
    for (int is = 0; is < 2; is++) {
      int c = is * 256 + t;
      int row = c >> 2, kc = c & 3;
      gld_lds16(A + (size_t)(m0 + row) * K + k0 + kc * 8, &lA[c * 8]);
      gld_lds16(B + (size_t)(n0 + row) * K + k0 + kc * 8, &lB[c * 8]);
    }
    __syncthreads();
    bf16_8 af[4], bfr[4];
#pragma unroll
    for (int i = 0; i < 4; i++)
      af[i] = *(const bf16_8*)&lA[(wrow + i * 16 + lrow) * BK + quad * 8];
#pragma unroll
    for (int j = 0; j < 4; j++)
      bfr[j] = *(const bf16_8*)&lB[(wcol + j * 16 + lrow) * BK + quad * 8];
#pragma unroll
    for (int i = 0; i < 4; i++)
#pragma unroll
      for (int j = 0; j < 4; j++)
        acc[i][j] = __builtin_amdgcn_mfma_f32_16x16x32_bf16(af[i], bfr[j], acc[i][j], 0, 0, 0);
  }

  // Epilogue. D mapping: row = quad*4 + reg, col = lrow (m89-verified).
  size_t cOff = (size_t)b * strideC;
#pragma unroll
  for (int i = 0; i < 4; i++) {
#pragma unroll
    for (int r = 0; r < 4; r++) {
      int gm = m0 + wrow + i * 16 + quad * 4 + r;
      float rowb = (BIAS_MODE == 2) ? bias[gm] : 0.f;
#pragma unroll
      for (int j = 0; j < 4; j++) {
        int gn = n0 + wcol + j * 16 + lrow;
        float v = acc[i][j][r] * alpha;
        if (BIAS_MODE == 1) v += bias[gn];
        if (BIAS_MODE == 2) v += rowb;
        if (RESID) v += resid[(size_t)b * strideR + (size_t)gm * N + gn];
        if (OUT_BF16)
          ((__bf16*)Cout)[cOff + (size_t)gm * N + gn] = (__bf16)v;
        else
          ((float*)Cout)[cOff + (size_t)gm * N + gn] = v;
      }
    }
  }
}

// ---------------- Softmax over rows of S (bf16, in place) ----------------
__global__ __launch_bounds__(256) void softmax_rows(__bf16* __restrict__ S) {
  __bf16* row = S + (size_t)blockIdx.x * NS;
  const int t = threadIdx.x;
  bf16_8 c0 = *(const bf16_8*)&row[t * 8];
  bf16_8 c1 = *(const bf16_8*)&row[2048 + t * 8];
  float v[16];
#pragma unroll
  for (int i = 0; i < 8; i++) { v[i] = (float)c0[i]; v[8 + i] = (float)c1[i]; }
  float mx = v[0];
#pragma unroll
  for (int i = 1; i < 16; i++) mx = fmaxf(mx, v[i]);
#pragma unroll
  for (int off = 32; off > 0; off >>= 1) mx = fmaxf(mx, __shfl_down(mx, off, 64));
  __shared__ float redm[4], reds[4];
  int wave = t >> 6, lane = t & 63;
  if (lane == 0) redm[wave] = mx;
  __syncthreads();
  mx = fmaxf(fmaxf(redm[0], redm[1]), fmaxf(redm[2], redm[3]));
  float sum = 0.f;
#pragma unroll
  for (int i = 0; i < 16; i++) { v[i] = __expf(v[i] - mx); sum += v[i]; }
#pragma unroll
  for (int off = 32; off > 0; off >>= 1) sum += __shfl_down(sum, off, 64);
  if (lane == 0) reds[wave] = sum;
  __syncthreads();
  float inv = 1.f / (reds[0] + reds[1] + reds[2] + reds[3]);
  bf16_8 o0, o1;
#pragma unroll
  for (int i = 0; i < 8; i++) {
    o0[i] = (__bf16)(v[i] * inv);
    o1[i] = (__bf16)(v[8 + i] * inv);
  }
  *(bf16_8*)&row[t * 8] = o0;
  *(bf16_8*)&row[2048 + t * 8] = o1;
}

extern "C" void kernel_launch(void* const* d_in, const int* in_sizes, int n_in,
                              void* d_out, int out_size, void* d_ws, size_t ws_size,
                              hipStream_t stream) {
  const float* x = (const float*)d_in[0];
  const float* gamma = (const float*)d_in[1];
  const float* beta = (const float*)d_in[2];
  const float* Wq = (const float*)d_in[3];
  const float* bq = (const float*)d_in[4];
  const float* Wk = (const float*)d_in[5];
  const float* bk = (const float*)d_in[6];
  const float* Wv = (const float*)d_in[7];
  const float* bv = (const float*)d_in[8];
  const float* Wo = (const float*)d_in[9];
  const float* bo = (const float*)d_in[10];
  float* out = (float*)d_out;

  // Workspace carve-up (~106 MiB total).
  char* ws = (char*)d_ws;
  __bf16* hnT = (__bf16*)(ws + 0);           // [B][NS][CC] 8 MiB
  __bf16* qT  = (__bf16*)(ws + 8388608);     // [B][NS][CC]
  __bf16* kT  = (__bf16*)(ws + 16777216);    // [B][NS][CC]
  __bf16* vv  = (__bf16*)(ws + 25165824);    // [B][CC][NS]
  __bf16* aoT = (__bf16*)(ws + 33554432);    // [B][NS][CC]
  __bf16* Sb  = (__bf16*)(ws + 41943040);    // [B][NS][NS] 64 MiB
  __bf16* Wqb = (__bf16*)(ws + 109051904);
  __bf16* Wkb = (__bf16*)(ws + 109576192);
  __bf16* Wvb = (__bf16*)(ws + 110100480);
  __bf16* Wob = (__bf16*)(ws + 110624768);
  float* stats = (float*)(ws + 111149056);   // [B*32][2]

  const long long sBNC = (long long)NS * CC;   // per-batch hnT/qT/kT/aoT stride
  const long long sBCN = (long long)CC * NS;   // per-batch v / x / out stride
  const long long sBNN = (long long)NS * NS;   // per-batch S stride
  const float scale = 0.044194173824159216f;   // 512^-0.5

  cvt_w<<<1024, 256, 0, stream>>>(Wq, Wk, Wv, Wo, Wqb, Wkb, Wvb, Wob);
  gn_stats<<<BB * NGROUP, 256, 0, stream>>>(x, stats);
  gn_apply_t<<<dim3(NS / 32, CC / 32, BB), dim3(32, 8), 0, stream>>>(x, stats, gamma, beta, hnT);

  // qT[n,o] = sum_c hnT[n,c] Wq[o,c] + bq[o]   (bias over col)
  gemm_bt<true, 1, false><<<dim3(CC / TILE, NS / TILE, BB), 256, 0, stream>>>(
      hnT, Wqb, qT, bq, nullptr, CC, CC, sBNC, 0, sBNC, 0, 1.f);
  gemm_bt<true, 1, false><<<dim3(CC / TILE, NS / TILE, BB), 256, 0, stream>>>(
      hnT, Wkb, kT, bk, nullptr, CC, CC, sBNC, 0, sBNC, 0, 1.f);
  // v[o,n] = sum_c Wv[o,c] hnT[n,c] + bv[o]    (bias over row)
  gemm_bt<true, 2, false><<<dim3(NS / TILE, CC / TILE, BB), 256, 0, stream>>>(
      Wvb, hnT, vv, bv, nullptr, NS, CC, 0, sBNC, sBCN, 0, 1.f);
  // S[i,j] = scale * sum_c qT[i,c] kT[j,c]
  gemm_bt<true, 0, false><<<dim3(NS / TILE, NS / TILE, BB), 256, 0, stream>>>(
      qT, kT, Sb, nullptr, nullptr, NS, CC, sBNC, sBNC, sBNN, 0, scale);
  softmax_rows<<<BB * NS, 256, 0, stream>>>(Sb);
  // aoT[i,c] = sum_j attn[i,j] v[c,j]
  gemm_bt<true, 0, false><<<dim3(CC / TILE, NS / TILE, BB), 256, 0, stream>>>(
      Sb, vv, aoT, nullptr, nullptr, CC, NS, sBNN, sBCN, sBNC, 0, 1.f);
  // out[o,n] = x[o,n] + sum_c Wo[o,c] aoT[n,c] + bo[o]
  gemm_bt<false, 2, true><<<dim3(NS / TILE, CC / TILE, BB), 256, 0, stream>>>(
      Wob, aoT, out, bo, x, NS, CC, 0, sBNC, sBCN, sBCN, 1.f);
}

// Round 2
// 297.182 us; speedup vs baseline: 1.1861x; 1.1861x over previous
//
#include <hip/hip_runtime.h>

// Problem constants: x [B=2, C=512, H=64, W=64], 32 groups, N = H*W = 4096.
#define BB 2
#define CC 512
#define NS 4096
#define NGROUP 32
#define TILE 128
#define BK 32

typedef __bf16 bf16_8 __attribute__((ext_vector_type(8)));
typedef __bf16 bf16_4 __attribute__((ext_vector_type(4)));
typedef float f32_4 __attribute__((ext_vector_type(4)));

__device__ __forceinline__ void gld_lds16(const __bf16* g, __bf16* l) {
  __builtin_amdgcn_global_load_lds(
      (const __attribute__((address_space(1))) unsigned int*)g,
      (__attribute__((address_space(3))) unsigned int*)l, 16, 0, 0);
}

// ---------------- GroupNorm ----------------
__global__ __launch_bounds__(256) void gn_stats(const float* __restrict__ x,
                                                float* __restrict__ stats) {
  const float4* p = (const float4*)(x + (size_t)blockIdx.x * 65536);
  float s = 0.f, q = 0.f;
  for (int i = threadIdx.x; i < 16384; i += 256) {
    float4 v = p[i];
    s += v.x + v.y + v.z + v.w;
    q += v.x * v.x + v.y * v.y + v.z * v.z + v.w * v.w;
  }
#pragma unroll
  for (int off = 32; off > 0; off >>= 1) {
    s += __shfl_down(s, off, 64);
    q += __shfl_down(q, off, 64);
  }
  __shared__ float ls[4], lq[4];
  int wave = threadIdx.x >> 6, lane = threadIdx.x & 63;
  if (lane == 0) { ls[wave] = s; lq[wave] = q; }
  __syncthreads();
  if (threadIdx.x == 0) {
    float S = ls[0] + ls[1] + ls[2] + ls[3];
    float Q = lq[0] + lq[1] + lq[2] + lq[3];
    float mean = S * (1.f / 65536.f);
    float var = Q * (1.f / 65536.f) - mean * mean;
    stats[blockIdx.x * 2] = mean;
    stats[blockIdx.x * 2 + 1] = rsqrtf(var + 1e-6f);
  }
}

// Normalize + transpose: x[b][c][n] (fp32) -> hnT[b][n][c] (bf16), 32x32 tiles via LDS.
__global__ __launch_bounds__(256) void gn_apply_t(const float* __restrict__ x,
                                                  const float* __restrict__ stats,
                                                  const float* __restrict__ gamma,
                                                  const float* __restrict__ beta,
                                                  __bf16* __restrict__ hnT) {
  __shared__ float tile[32][33];
  int b = blockIdx.z;
  int c0 = blockIdx.y * 32;
  int n0 = blockIdx.x * 32;
  int tx = threadIdx.x;  // 0..31
  int ty = threadIdx.y;  // 0..7
  const float* xb = x + (size_t)b * CC * NS;
#pragma unroll
  for (int i = 0; i < 4; i++) {
    int c = c0 + ty + i * 8;
    float mean = stats[(b * NGROUP + (c >> 4)) * 2 + 0];
    float rstd = stats[(b * NGROUP + (c >> 4)) * 2 + 1];
    float v = xb[(size_t)c * NS + n0 + tx];
    tile[ty + i * 8][tx] = (v - mean) * rstd * gamma[c] + beta[c];
  }
  __syncthreads();
  __bf16* out = hnT + (size_t)b * NS * CC;
#pragma unroll
  for (int i = 0; i < 4; i++) {
    int n = n0 + ty + i * 8;
    out[(size_t)n * CC + c0 + tx] = (__bf16)tile[tx][ty + i * 8];
  }
}

// fp32 -> bf16 weight conversion for the four 512x512 weights.
__global__ __launch_bounds__(256) void cvt_w(const float* __restrict__ w0, const float* __restrict__ w1,
                                             const float* __restrict__ w2, const float* __restrict__ w3,
                                             __bf16* __restrict__ o0, __bf16* __restrict__ o1,
                                             __bf16* __restrict__ o2, __bf16* __restrict__ o3) {
  int tsel = blockIdx.x >> 8;
  int i = (blockIdx.x & 255) * 256 + threadIdx.x;
  const float* src = tsel == 0 ? w0 : tsel == 1 ? w1 : tsel == 2 ? w2 : w3;
  __bf16* dst = tsel == 0 ? o0 : tsel == 1 ? o1 : tsel == 2 ? o2 : o3;
  float4 v = ((const float4*)src)[i];
  bf16_4 r;
  r[0] = (__bf16)v.x; r[1] = (__bf16)v.y; r[2] = (__bf16)v.z; r[3] = (__bf16)v.w;
  ((bf16_4*)dst)[i] = r;
}

// ---------------- Shared GEMM core ----------------
// Computes 128x128 tile: acc[m,n] += sum_k A[m,k]*B[n,k]. A/B pre-offset to tile
// origin. LDS K-chunks XOR-swizzled ((row>>1)&3) to kill ds_read_b128 bank
// conflicts; legal with global_load_lds because we permute the GLOBAL source
// address per lane, keeping the LDS destination lane-linear.
__device__ __forceinline__ void gemm_core(const __bf16* __restrict__ A, const __bf16* __restrict__ B,
                                          int K, int lda, int ldb,
                                          __bf16* lA, __bf16* lB, f32_4 (&acc)[4][4]) {
  const int t = threadIdx.x;
  const int lane = t & 63;
  const int wave = t >> 6;
  const int lrow = lane & 15, quad = lane >> 4;
  const int wrow = (wave >> 1) * 64, wcol = (wave & 1) * 64;
  const int co = (quad ^ ((lrow >> 1) & 3)) * 8;   // swizzled read chunk
  const int r0 = t >> 2;
  const int kp = ((t & 3) ^ ((t >> 3) & 3)) * 8;   // swizzled staged global chunk
  const __bf16* pA0 = A + (size_t)r0 * lda + kp;
  const __bf16* pA1 = A + (size_t)(r0 + 64) * lda + kp;
  const __bf16* pB0 = B + (size_t)r0 * ldb + kp;
  const __bf16* pB1 = B + (size_t)(r0 + 64) * ldb + kp;
  for (int k0 = 0; k0 < K; k0 += BK) {
    __syncthreads();
    gld_lds16(pA0 + k0, &lA[t * 8]);
    gld_lds16(pA1 + k0, &lA[2048 + t * 8]);
    gld_lds16(pB0 + k0, &lB[t * 8]);
    gld_lds16(pB1 + k0, &lB[2048 + t * 8]);
    __syncthreads();
    bf16_8 af[4], bfr[4];
#pragma unroll
    for (int i = 0; i < 4; i++)
      af[i] = *(const bf16_8*)&lA[(wrow + i * 16 + lrow) * BK + co];
#pragma unroll
    for (int j = 0; j < 4; j++)
      bfr[j] = *(const bf16_8*)&lB[(wcol + j * 16 + lrow) * BK + co];
#pragma unroll
    for (int i = 0; i < 4; i++)
#pragma unroll
      for (int j = 0; j < 4; j++)
        acc[i][j] = __builtin_amdgcn_mfma_f32_16x16x32_bf16(af[i], bfr[j], acc[i][j], 0, 0, 0);
  }
}

// ---------------- Generic GEMM (S-matrix, output projection) ----------------
template <bool OUT_BF16, int BIAS_MODE /*0 none,1 col,2 row*/, bool RESID>
__global__ __launch_bounds__(256) void gemm_bt(const __bf16* __restrict__ A,
                                               const __bf16* __restrict__ B,
                                               void* __restrict__ Cout,
                                               const float* __restrict__ bias,
                                               const float* __restrict__ resid,
                                               int N, int K, int lda, int ldb,
                                               long long strideA, long long strideB,
                                               long long strideC, long long strideR,
                                               float alpha) {
  __shared__ __bf16 lA[TILE * BK];
  __shared__ __bf16 lB[TILE * BK];
  const int t = threadIdx.x;
  const int b = blockIdx.z;
  const int m0 = blockIdx.y * TILE;
  const int n0 = blockIdx.x * TILE;
  const __bf16* Ap = A + (size_t)b * strideA + (size_t)m0 * lda;
  const __bf16* Bp = B + (size_t)b * strideB + (size_t)n0 * ldb;

  f32_4 acc[4][4];
#pragma unroll
  for (int i = 0; i < 4; i++)
#pragma unroll
    for (int j = 0; j < 4; j++) acc[i][j] = {0.f, 0.f, 0.f, 0.f};

  gemm_core(Ap, Bp, K, lda, ldb, lA, lB, acc);

  const int lane = t & 63;
  const int lrow = lane & 15, quad = lane >> 4;
  const int wave = t >> 6;
  const int wrow = (wave >> 1) * 64, wcol = (wave & 1) * 64;
  size_t cOff = (size_t)b * strideC;
#pragma unroll
  for (int i = 0; i < 4; i++) {
#pragma unroll
    for (int r = 0; r < 4; r++) {
      int gm = m0 + wrow + i * 16 + quad * 4 + r;
      float rowb = (BIAS_MODE == 2) ? bias[gm] : 0.f;
#pragma unroll
      for (int j = 0; j < 4; j++) {
        int gn = n0 + wcol + j * 16 + lrow;
        float v = acc[i][j][r] * alpha;
        if (BIAS_MODE == 1) v += bias[gn];
        if (BIAS_MODE == 2) v += rowb;
        if (RESID) v += resid[(size_t)b * strideR + (size_t)gm * N + gn];
        if (OUT_BF16)
          ((__bf16*)Cout)[cOff + (size_t)gm * N + gn] = (__bf16)v;
        else
          ((float*)Cout)[cOff + (size_t)gm * N + gn] = v;
      }
    }
  }
}

// ---------------- Fused Q/K/V projections (one dispatch, 768 blocks) ----------
// blockIdx.x in [0,384): sel = x>>7 (0=q,1=k,2=v), r = x&127. blockIdx.z = batch.
__global__ __launch_bounds__(256) void qkv_gemm(const __bf16* __restrict__ hnT,
                                                const __bf16* __restrict__ Wq,
                                                const __bf16* __restrict__ Wk,
                                                const __bf16* __restrict__ Wv,
                                                const float* __restrict__ bq,
                                                const float* __restrict__ bk,
                                                const float* __restrict__ bv,
                                                __bf16* __restrict__ qT,
                                                __bf16* __restrict__ kT,
                                                __bf16* __restrict__ vv) {
  __shared__ __bf16 lA[TILE * BK];
  __shared__ __bf16 lB[TILE * BK];
  const int b = blockIdx.z;
  const int id = blockIdx.x;
  const int sel = id >> 7;
  const int r = id & 127;
  const long long sBNC = (long long)NS * CC;
  const long long sBCN = (long long)CC * NS;

  int m0, n0, N;
  const __bf16 *Ap, *Bp;
  __bf16* Cp;
  const float* bias;
  if (sel < 2) {  // q/k: out[n, o] = sum_c hnT[n,c] W[o,c] + b[o]
    m0 = (r >> 2) * TILE;          // over NS
    n0 = (r & 3) * TILE;           // over CC
    Ap = hnT + (size_t)b * sBNC + (size_t)m0 * CC;
    Bp = (sel == 0 ? Wq : Wk) + (size_t)n0 * CC;
    Cp = (sel == 0 ? qT : kT) + (size_t)b * sBNC;
    bias = (sel == 0 ? bq : bk);
    N = CC;
  } else {  // v: out[o, n] = sum_c Wv[o,c] hnT[n,c] + bv[o]
    m0 = (r & 3) * TILE;           // over CC
    n0 = (r >> 2) * TILE;          // over NS
    Ap = Wv + (size_t)m0 * CC;
    Bp = hnT + (size_t)b * sBNC + (size_t)n0 * CC;
    Cp = vv + (size_t)b * sBCN;
    bias = bv;
    N = NS;
  }

  f32_4 acc[4][4];
#pragma unroll
  for (int i = 0; i < 4; i++)
#pragma unroll
    for (int j = 0; j < 4; j++) acc[i][j] = {0.f, 0.f, 0.f, 0.f};

  gemm_core(Ap, Bp, CC, CC, CC, lA, lB, acc);

  const int t = threadIdx.x;
  const int lane = t & 63;
  const int lrow = lane & 15, quad = lane >> 4;
  const int wave = t >> 6;
  const int wrow = (wave >> 1) * 64, wcol = (wave & 1) * 64;
#pragma unroll
  for (int i = 0; i < 4; i++) {
#pragma unroll
    for (int r2 = 0; r2 < 4; r2++) {
      int gm = m0 + wrow + i * 16 + quad * 4 + r2;
      float rowb = (sel == 2) ? bias[gm] : 0.f;
#pragma unroll
      for (int j = 0; j < 4; j++) {
        int gn = n0 + wcol + j * 16 + lrow;
        float v = acc[i][j][r2] + (sel < 2 ? bias[gn] : rowb);
        Cp[(size_t)gm * N + gn] = (__bf16)v;
      }
    }
  }
}

// ---------------- attn*V split-K GEMM (512 blocks, 2/CU) ----------------
// z = split*2 + b. Partial aoT[i,c] (bf16) over half the j range.
__global__ __launch_bounds__(256) void ao_split(const __bf16* __restrict__ Sb,
                                                const __bf16* __restrict__ vv,
                                                __bf16* __restrict__ p0,
                                                __bf16* __restrict__ p1) {
  __shared__ __bf16 lA[TILE * BK];
  __shared__ __bf16 lB[TILE * BK];
  const int b = blockIdx.z & 1;
  const int split = blockIdx.z >> 1;
  const int m0 = blockIdx.y * TILE;   // over NS (i)
  const int n0 = blockIdx.x * TILE;   // over CC (c)
  const long long sBNN = (long long)NS * NS;
  const long long sBCN = (long long)CC * NS;
  const long long sBNC = (long long)NS * CC;
  const __bf16* Ap = Sb + (size_t)b * sBNN + (size_t)m0 * NS + (size_t)split * 2048;
  const __bf16* Bp = vv + (size_t)b * sBCN + (size_t)n0 * NS + (size_t)split * 2048;
  __bf16* Cp = (split ? p1 : p0) + (size_t)b * sBNC;

  f32_4 acc[4][4];
#pragma unroll
  for (int i = 0; i < 4; i++)
#pragma unroll
    for (int j = 0; j < 4; j++) acc[i][j] = {0.f, 0.f, 0.f, 0.f};

  gemm_core(Ap, Bp, 2048, NS, NS, lA, lB, acc);

  const int t = threadIdx.x;
  const int lane = t & 63;
  const int lrow = lane & 15, quad = lane >> 4;
  const int wave = t >> 6;
  const int wrow = (wave >> 1) * 64, wcol = (wave & 1) * 64;
#pragma unroll
  for (int i = 0; i < 4; i++) {
#pragma unroll
    for (int r = 0; r < 4; r++) {
      int gm = m0 + wrow + i * 16 + quad * 4 + r;
#pragma unroll
      for (int j = 0; j < 4; j++) {
        int gn = n0 + wcol + j * 16 + lrow;
        Cp[(size_t)gm * CC + gn] = (__bf16)acc[i][j][r];
      }
    }
  }
}

// p0 + p1 -> aoT (bf16), 4.19M elements.
__global__ __launch_bounds__(256) void reduce_ao(const __bf16* __restrict__ p0,
                                                 const __bf16* __restrict__ p1,
                                                 __bf16* __restrict__ o) {
  int i = blockIdx.x * 256 + threadIdx.x;
  bf16_8 a = ((const bf16_8*)p0)[i];
  bf16_8 c = ((const bf16_8*)p1)[i];
  bf16_8 r;
#pragma unroll
  for (int k = 0; k < 8; k++) r[k] = (__bf16)((float)a[k] + (float)c[k]);
  ((bf16_8*)o)[i] = r;
}

// ---------------- Softmax over rows of S (bf16, in place) ----------------
__global__ __launch_bounds__(256) void softmax_rows(__bf16* __restrict__ S) {
  __bf16* row = S + (size_t)blockIdx.x * NS;
  const int t = threadIdx.x;
  bf16_8 c0 = *(const bf16_8*)&row[t * 8];
  bf16_8 c1 = *(const bf16_8*)&row[2048 + t * 8];
  float v[16];
#pragma unroll
  for (int i = 0; i < 8; i++) { v[i] = (float)c0[i]; v[8 + i] = (float)c1[i]; }
  float mx = v[0];
#pragma unroll
  for (int i = 1; i < 16; i++) mx = fmaxf(mx, v[i]);
#pragma unroll
  for (int off = 32; off > 0; off >>= 1) mx = fmaxf(mx, __shfl_down(mx, off, 64));
  __shared__ float redm[4], reds[4];
  int wave = t >> 6, lane = t & 63;
  if (lane == 0) redm[wave] = mx;
  __syncthreads();
  mx = fmaxf(fmaxf(redm[0], redm[1]), fmaxf(redm[2], redm[3]));
  float sum = 0.f;
#pragma unroll
  for (int i = 0; i < 16; i++) { v[i] = __expf(v[i] - mx); sum += v[i]; }
#pragma unroll
  for (int off = 32; off > 0; off >>= 1) sum += __shfl_down(sum, off, 64);
  if (lane == 0) reds[wave] = sum;
  __syncthreads();
  float inv = 1.f / (reds[0] + reds[1] + reds[2] + reds[3]);
  bf16_8 o0, o1;
#pragma unroll
  for (int i = 0; i < 8; i++) {
    o0[i] = (__bf16)(v[i] * inv);
    o1[i] = (__bf16)(v[8 + i] * inv);
  }
  *(bf16_8*)&row[t * 8] = o0;
  *(bf16_8*)&row[2048 + t * 8] = o1;
}

extern "C" void kernel_launch(void* const* d_in, const int* in_sizes, int n_in,
                              void* d_out, int out_size, void* d_ws, size_t ws_size,
                              hipStream_t stream) {
  const float* x = (const float*)d_in[0];
  const float* gamma = (const float*)d_in[1];
  const float* beta = (const float*)d_in[2];
  const float* Wq = (const float*)d_in[3];
  const float* bq = (const float*)d_in[4];
  const float* Wk = (const float*)d_in[5];
  const float* bk = (const float*)d_in[6];
  const float* Wv = (const float*)d_in[7];
  const float* bv = (const float*)d_in[8];
  const float* Wo = (const float*)d_in[9];
  const float* bo = (const float*)d_in[10];
  float* out = (float*)d_out;

  char* ws = (char*)d_ws;
  __bf16* hnT = (__bf16*)(ws + 0);           // [B][NS][CC] 8 MiB; reused as p0
  __bf16* qT  = (__bf16*)(ws + 8388608);     // [B][NS][CC]; reused as p1
  __bf16* kT  = (__bf16*)(ws + 16777216);
  __bf16* vv  = (__bf16*)(ws + 25165824);    // [B][CC][NS]
  __bf16* aoT = (__bf16*)(ws + 33554432);    // [B][NS][CC]
  __bf16* Sb  = (__bf16*)(ws + 41943040);    // [B][NS][NS] 64 MiB
  __bf16* Wqb = (__bf16*)(ws + 109051904);
  __bf16* Wkb = (__bf16*)(ws + 109576192);
  __bf16* Wvb = (__bf16*)(ws + 110100480);
  __bf16* Wob = (__bf16*)(ws + 110624768);
  float* stats = (float*)(ws + 111149056);
  __bf16* p0 = hnT;   // dead after qkv_gemm
  __bf16* p1 = qT;    // dead after S gemm

  const long long sBNC = (long long)NS * CC;
  const long long sBCN = (long long)CC * NS;
  const long long sBNN = (long long)NS * NS;
  const float scale = 0.044194173824159216f;  // 512^-0.5

  cvt_w<<<1024, 256, 0, stream>>>(Wq, Wk, Wv, Wo, Wqb, Wkb, Wvb, Wob);
  gn_stats<<<BB * NGROUP, 256, 0, stream>>>(x, stats);
  gn_apply_t<<<dim3(NS / 32, CC / 32, BB), dim3(32, 8), 0, stream>>>(x, stats, gamma, beta, hnT);

  // Fused Q/K/V projections: 768 blocks (3/CU).
  qkv_gemm<<<dim3(384, 1, BB), 256, 0, stream>>>(hnT, Wqb, Wkb, Wvb, bq, bk, bv, qT, kT, vv);

  // S[i,j] = scale * sum_c qT[i,c] kT[j,c]   (2048 blocks)
  gemm_bt<true, 0, false><<<dim3(NS / TILE, NS / TILE, BB), 256, 0, stream>>>(
      qT, kT, Sb, nullptr, nullptr, NS, CC, CC, CC, sBNC, sBNC, sBNN, 0, scale);

  softmax_rows<<<BB * NS, 256, 0, stream>>>(Sb);

  // aoT[i,c] = sum_j attn[i,j] v[c,j] — split-K=2 (512 blocks), bf16 partials.
  ao_split<<<dim3(CC / TILE, NS / TILE, 2 * BB), 256, 0, stream>>>(Sb, vv, p0, p1);
  reduce_ao<<<2048, 256, 0, stream>>>(p0, p1, aoT);

  // out[o,n] = x[o,n] + sum_c Wo[o,c] aoT[n,c] + bo[o]   (256 blocks)
  gemm_bt<false, 2, true><<<dim3(NS / TILE, CC / TILE, BB), 256, 0, stream>>>(
      Wob, aoT, out, bo, x, NS, CC, CC, CC, 0, sBNC, sBCN, sBCN, 1.f);
}